// Round 9
// baseline (244.180 us; speedup 1.0000x reference)
//
#include <hip/hip_runtime.h>
#include <stdint.h>

// Q2Linear int8 path, 2 dispatches. R9: 4 blocks/CU for phase overlap.
//   prep: blocks 0..1023    — per-row quantize x fp32 -> i8 (q = rowmax/127)
//         blocks 1024..5119 — pack w int32 {-2..1} -> i8 (exact, coalesced)
//   q8_gemm: i8 MFMA 16x16x64, tile 64m x 64n, BK=128 (= one scale block),
//            grid 1024 = 4 blocks/CU (LDS 37 KB), 16 waves/CU.
//            Wave = 64m x 16n -> one scale per lane per slab.
//            Scales staged once as bf16 in padded LDS (error ~0.2% per slab,
//            well inside budget). R8's 2-bit unpack reverted: VALU on MFMA
//            waves cost more than the L2 bytes it saved.

#define MM 1024
#define NN 4096
#define KK 4096
#define BK 128

typedef __attribute__((ext_vector_type(4))) int intx4;
typedef __attribute__((ext_vector_type(4))) float floatx4;

typedef const __attribute__((address_space(1))) void global_cvoid;
typedef __attribute__((address_space(3))) void lds_void;

__device__ __forceinline__ unsigned short f2bf(float f) {
    union { float f; unsigned u; } v; v.f = f;
    return (unsigned short)((v.u + 0x7FFFu + ((v.u >> 16) & 1u)) >> 16);  // RNE
}
__device__ __forceinline__ float bf2f(unsigned short b) {
    union { unsigned u; float f; } v; v.u = ((unsigned)b) << 16;
    return v.f;
}

// ---- prep: quantize x (blocks < MM) OR pack w -> i8 --------------------------
__global__ __launch_bounds__(256) void prep(const float* __restrict__ x,
                                            const int* __restrict__ wq,
                                            char* __restrict__ xq,
                                            float* __restrict__ qrow,
                                            char* __restrict__ wb) {
    const int tid = threadIdx.x;
    if (blockIdx.x < MM) {
        const int m = blockIdx.x;
        const float* xr = x + (size_t)m * KK;
        floatx4 v[4];
        float amax = 0.f;
#pragma unroll
        for (int c = 0; c < 4; ++c) {
            v[c] = *(const floatx4*)(xr + (c * 256 + tid) * 4);
#pragma unroll
            for (int e = 0; e < 4; ++e) amax = fmaxf(amax, fabsf(v[c][e]));
        }
#pragma unroll
        for (int off = 32; off; off >>= 1) amax = fmaxf(amax, __shfl_down(amax, off));
        __shared__ float wmax[4];
        if ((tid & 63) == 0) wmax[tid >> 6] = amax;
        __syncthreads();
        amax = fmaxf(fmaxf(wmax[0], wmax[1]), fmaxf(wmax[2], wmax[3]));
        amax = fmaxf(amax, 1e-20f);
        const float qinv = 127.0f / amax;
        if (tid == 0) qrow[m] = amax / 127.0f;
#pragma unroll
        for (int c = 0; c < 4; ++c) {
            int p = 0;
#pragma unroll
            for (int e = 0; e < 4; ++e) {
                float r = rintf(v[c][e] * qinv);
                r = fminf(fmaxf(r, -127.f), 127.f);
                p |= ((int)r & 255) << (8 * e);
            }
            *(int*)(xq + (size_t)m * KK + (c * 256 + tid) * 4) = p;
        }
    } else {
        // pack w: fully coalesced (lane-consecutive 16B reads / 4B writes)
        const int blk = blockIdx.x - MM;
#pragma unroll
        for (int c = 0; c < 4; ++c) {
            size_t c4 = (size_t)blk * 1024 + c * 256 + tid;  // intx4-chunk id
            intx4 a = ((const intx4*)wq)[c4];
            ((int*)wb)[c4] = (a[0] & 255) | ((a[1] & 255) << 8) |
                             ((a[2] & 255) << 16) | (a[3] << 24);
        }
    }
}

// ---- GEMM: 64x64 tile, 4 waves (each 64m x 16n), double-buffered LDS ---------
__global__ __launch_bounds__(256) void q8_gemm(const char* __restrict__ xq,
                                               const char* __restrict__ wb,
                                               const float* __restrict__ qrow,
                                               const float* __restrict__ scales,
                                               float* __restrict__ out) {
    __shared__ char As[2][64 * BK];          // 8 KB each
    __shared__ char Bs[2][64 * BK];          // 8 KB each
    __shared__ unsigned short Sl[64 * 33];   // bf16 scales [n_local][slab], +1 pad
    // total ~37 KB -> 4 blocks/CU

    const int tid  = threadIdx.x;
    const int lane = tid & 63;
    const int wave = tid >> 6;
    const int r16  = lane & 15;
    const int quad = lane >> 4;
    const int sw   = r16 & 7;
    const int wn   = wave * 16;        // wave's n offset within tile

    // XCD pinning: bid&7 -> XCD; each XCD owns an 8-n-tile strip (512 cols,
    // 2.1MB i8 B-strip L2-resident) x all 16 m-tiles (xq 4MB also L2-resident).
    const int bid = blockIdx.x;
    const int xcd = bid & 7, loc = bid >> 3;   // loc 0..127
    const int nT = xcd * 8 + (loc & 7);        // 0..63
    const int mT = loc >> 3;                   // 0..15
    const int mBase = mT * 64, nBase = nT * 64;

    // staging address permute -> XOR-swizzled LDS tile (verified, 0 conflicts)
    const int rg = lane >> 3;
    const int cs = (lane & 7) ^ rg;
    const char* gA = xq + (size_t)(mBase + wave * 16 + rg) * KK + cs * 16;
    const char* gB = wb + (size_t)(nBase + wave * 16 + rg) * KK + cs * 16;
    const int ldsRow = wave * 16;

    floatx4 facc[4];
#pragma unroll
    for (int i = 0; i < 4; ++i) facc[i] = (floatx4){0.f, 0.f, 0.f, 0.f};

#define STAGE(BUF, SLAB)                                                        \
    {                                                                           \
        _Pragma("unroll")                                                       \
        for (int t = 0; t < 2; ++t)                                             \
            __builtin_amdgcn_global_load_lds(                                   \
                (global_cvoid*)(gA + (size_t)(t * 8) * KK + (SLAB) * BK),       \
                (lds_void*)&As[BUF][(ldsRow + t * 8) * BK], 16, 0, 0);          \
        _Pragma("unroll")                                                       \
        for (int t = 0; t < 2; ++t)                                             \
            __builtin_amdgcn_global_load_lds(                                   \
                (global_cvoid*)(gB + (size_t)(t * 8) * KK + (SLAB) * BK),       \
                (lds_void*)&Bs[BUF][(ldsRow + t * 8) * BK], 16, 0, 0);          \
    }

#define COMPUTE(BUF, SLAB)                                                      \
    {                                                                           \
        float sf = bf2f(Sl[(wn + r16) * 33 + (SLAB)]);                          \
        intx4 iacc[4];                                                          \
        _Pragma("unroll")                                                       \
        for (int kp = 0; kp < 2; ++kp) {                                        \
            intx4 av[4], bv;                                                    \
            _Pragma("unroll")                                                   \
            for (int i = 0; i < 4; ++i)                                         \
                av[i] = *(const intx4*)&As[BUF][(i * 16 + r16) * BK +           \
                                               (((kp * 4 + quad) ^ sw) << 4)];  \
            bv = *(const intx4*)&Bs[BUF][(wn + r16) * BK +                      \
                                         (((kp * 4 + quad) ^ sw) << 4)];        \
            _Pragma("unroll")                                                   \
            for (int i = 0; i < 4; ++i)                                         \
                iacc[i] = __builtin_amdgcn_mfma_i32_16x16x64_i8(                \
                    av[i], bv, kp ? iacc[i] : (intx4){0, 0, 0, 0}, 0, 0, 0);    \
        }                                                                       \
        _Pragma("unroll")                                                       \
        for (int i = 0; i < 4; ++i)                                             \
            _Pragma("unroll")                                                   \
            for (int r = 0; r < 4; ++r)                                         \
                facc[i][r] += (float)iacc[i][r] * sf;                           \
    }

    STAGE(0, 0)
    // stage scales once: coalesced global read -> bf16 LDS (64x32 = 2048)
    for (int t = tid; t < 2048; t += 256) {
        int nl = t >> 5, b = t & 31;
        Sl[nl * 33 + b] = f2bf(scales[(size_t)(nBase + nl) * 32 + b]);
    }
    __syncthreads();

    const int NIT = KK / BK;  // 32
    for (int it = 0; it < NIT; it += 2) {
        if (it + 1 < NIT) STAGE(1, it + 1)
        COMPUTE(0, it)
        __syncthreads();
        if (it + 2 < NIT) STAGE(0, it + 2)
        COMPUTE(1, it + 1)
        __syncthreads();
    }

    // epilogue: C/D col = lane&15 (n), row = quad*4 + reg (m); fold q[m]
#pragma unroll
    for (int i = 0; i < 4; ++i) {
        floatx4 qv = *(const floatx4*)(qrow + mBase + i * 16 + quad * 4);
#pragma unroll
        for (int r = 0; r < 4; ++r) {
            int mg = mBase + i * 16 + quad * 4 + r;
            out[(size_t)mg * NN + nBase + wn + r16] = facc[i][r] * qv[r];
        }
    }
#undef STAGE
#undef COMPUTE
}

extern "C" void kernel_launch(void* const* d_in, const int* in_sizes, int n_in,
                              void* d_out, int out_size, void* d_ws, size_t ws_size,
                              hipStream_t stream) {
    const float* x      = (const float*)d_in[0];
    const int*   wq     = (const int*)d_in[1];
    const float* scales = (const float*)d_in[2];
    float*       out    = (float*)d_out;

    char*  xq   = (char*)d_ws;                                   // 4 MB
    float* qrow = (float*)((char*)d_ws + (size_t)MM * KK);       // 4 KB
    char*  wb   = (char*)d_ws + (size_t)MM * KK + 4096;          // 16.8 MB

    prep<<<MM + (size_t)NN * KK / 16 / 256, 256, 0, stream>>>(x, wq, xq, qrow, wb);
    q8_gemm<<<(MM / 64) * (NN / 64), 256, 0, stream>>>(xq, wb, qrow, scales, out);
}

// Round 10
// 184.229 us; speedup vs baseline: 1.3254x; 1.3254x over previous
//
#include <hip/hip_runtime.h>
#include <stdint.h>

// Q2Linear int8 path, 2 dispatches. R10 = R7 + A-operand LDS bypass.
//   prep: blocks 0..1023    — per-row quantize x fp32 -> i8 (q = rowmax/127)
//         blocks 1024..5119 — pack w int32 {-2..1} -> i8 (exact, coalesced)
//   q8_gemm: i8 MFMA 16x16x64, tile 64m x 128n, BK=128 (= one scale block),
//            512 blocks = 2/CU. B staged via global_load_lds into XOR-swizzled
//            dbuf LDS (verified, 0 conflicts). A fragments loaded DIRECT from
//            row-major xq to registers (16-row x 64B segments; 4 waves share
//            the same 8KB slab -> L1 broadcast). LDS traffic/slab-block drops
//            72->32 KB; barrier-gated DMA 6->4 loads.

#define MM 1024
#define NN 4096
#define KK 4096
#define BK 128

typedef __attribute__((ext_vector_type(4))) int intx4;
typedef __attribute__((ext_vector_type(4))) float floatx4;

typedef const __attribute__((address_space(1))) void global_cvoid;
typedef __attribute__((address_space(3))) void lds_void;

// ---- prep: quantize x (blocks < MM) OR pack w -> i8 --------------------------
__global__ __launch_bounds__(256) void prep(const float* __restrict__ x,
                                            const int* __restrict__ wq,
                                            char* __restrict__ xq,
                                            float* __restrict__ qrow,
                                            char* __restrict__ wb) {
    const int tid = threadIdx.x;
    if (blockIdx.x < MM) {
        const int m = blockIdx.x;
        const float* xr = x + (size_t)m * KK;
        floatx4 v[4];
        float amax = 0.f;
#pragma unroll
        for (int c = 0; c < 4; ++c) {
            v[c] = *(const floatx4*)(xr + (c * 256 + tid) * 4);
#pragma unroll
            for (int e = 0; e < 4; ++e) amax = fmaxf(amax, fabsf(v[c][e]));
        }
#pragma unroll
        for (int off = 32; off; off >>= 1) amax = fmaxf(amax, __shfl_down(amax, off));
        __shared__ float wmax[4];
        if ((tid & 63) == 0) wmax[tid >> 6] = amax;
        __syncthreads();
        amax = fmaxf(fmaxf(wmax[0], wmax[1]), fmaxf(wmax[2], wmax[3]));
        amax = fmaxf(amax, 1e-20f);
        const float qinv = 127.0f / amax;
        if (tid == 0) qrow[m] = amax / 127.0f;
#pragma unroll
        for (int c = 0; c < 4; ++c) {
            int p = 0;
#pragma unroll
            for (int e = 0; e < 4; ++e) {
                float r = rintf(v[c][e] * qinv);
                r = fminf(fmaxf(r, -127.f), 127.f);
                p |= ((int)r & 255) << (8 * e);
            }
            *(int*)(xq + (size_t)m * KK + (c * 256 + tid) * 4) = p;
        }
    } else {
        // pack w: fully coalesced (lane-consecutive 16B reads / 4B writes)
        const int blk = blockIdx.x - MM;
#pragma unroll
        for (int c = 0; c < 4; ++c) {
            size_t c4 = (size_t)blk * 1024 + c * 256 + tid;  // intx4-chunk id
            intx4 a = ((const intx4*)wq)[c4];
            ((int*)wb)[c4] = (a[0] & 255) | ((a[1] & 255) << 8) |
                             ((a[2] & 255) << 16) | (a[3] << 24);
        }
    }
}

// ---- GEMM: 64x128 tile, 4 waves (each 64m x 32n) -----------------------------
__global__ __launch_bounds__(256, 2) void q8_gemm(const char* __restrict__ xq,
                                                  const char* __restrict__ wb,
                                                  const float* __restrict__ qrow,
                                                  const float* __restrict__ scales,
                                                  float* __restrict__ out) {
    __shared__ char Bs[2][128 * BK];   // 16 KB each
    __shared__ float Sl[128 * 33];     // scales [n_local][block], +1 pad (16.9 KB)
    // total ~49 KB -> 2 blocks/CU (grid 512 = 2/CU)

    const int tid  = threadIdx.x;
    const int lane = tid & 63;
    const int wave = tid >> 6;
    const int r16  = lane & 15;
    const int quad = lane >> 4;
    const int sw   = r16 & 7;
    const int wn   = wave * 32;        // wave's n offset within tile

    // XCD pinning: bid&7 -> XCD; each XCD owns 4 n-tiles (512 cols, 2MB B-strip)
    const int bid = blockIdx.x;
    const int xcd = bid & 7, loc = bid >> 3;   // loc 0..63
    const int nT = xcd * 4 + (loc & 3);        // 0..31
    const int mT = loc >> 2;                   // 0..15
    const int mBase = mT * 64, nBase = nT * 128;

    // B staging address permute -> XOR-swizzled LDS tile (verified, 0 conflicts)
    const int rg = lane >> 3;
    const int cs = (lane & 7) ^ rg;
    const char* gB = wb + (size_t)(nBase + wave * 32 + rg) * KK + cs * 16;
    const int ldsRowB = wave * 32;

    // A direct-load per-lane base: row mBase + i*16 + r16, col slab*128 + kp*64 + quad*16
    const char* gAl = xq + (size_t)(mBase + r16) * KK + quad * 16;

    floatx4 facc[4][2];
#pragma unroll
    for (int i = 0; i < 4; ++i)
#pragma unroll
        for (int j = 0; j < 2; ++j) facc[i][j] = (floatx4){0.f, 0.f, 0.f, 0.f};

#define STAGE(BUF, SLAB)                                                        \
    {                                                                           \
        _Pragma("unroll")                                                       \
        for (int t = 0; t < 4; ++t)                                             \
            __builtin_amdgcn_global_load_lds(                                   \
                (global_cvoid*)(gB + (size_t)(t * 8) * KK + (SLAB) * BK),       \
                (lds_void*)&Bs[BUF][(ldsRowB + t * 8) * BK], 16, 0, 0);         \
    }

#define COMPUTE(BUF, SLAB)                                                      \
    {                                                                           \
        float sf0 = Sl[(wn + r16) * 33 + (SLAB)];                               \
        float sf1 = Sl[(wn + 16 + r16) * 33 + (SLAB)];                          \
        intx4 av[4][2];                                                         \
        _Pragma("unroll")                                                       \
        for (int i = 0; i < 4; ++i)                                             \
            _Pragma("unroll")                                                   \
            for (int kp = 0; kp < 2; ++kp)                                      \
                av[i][kp] = *(const intx4*)(gAl + (size_t)(i * 16) * KK +       \
                                            (SLAB) * BK + kp * 64);             \
        intx4 iacc[4][2];                                                       \
        _Pragma("unroll")                                                       \
        for (int kp = 0; kp < 2; ++kp) {                                        \
            intx4 bv[2];                                                        \
            _Pragma("unroll")                                                   \
            for (int j = 0; j < 2; ++j)                                         \
                bv[j] = *(const intx4*)&Bs[BUF][(wn + j * 16 + r16) * BK +      \
                                               (((kp * 4 + quad) ^ sw) << 4)];  \
            _Pragma("unroll")                                                   \
            for (int i = 0; i < 4; ++i)                                         \
                _Pragma("unroll")                                               \
                for (int j = 0; j < 2; ++j)                                     \
                    iacc[i][j] = __builtin_amdgcn_mfma_i32_16x16x64_i8(         \
                        av[i][kp], bv[j], kp ? iacc[i][j] : (intx4){0, 0, 0, 0},\
                        0, 0, 0);                                               \
        }                                                                       \
        _Pragma("unroll")                                                       \
        for (int i = 0; i < 4; ++i)                                             \
            _Pragma("unroll")                                                   \
            for (int r = 0; r < 4; ++r) {                                       \
                facc[i][0][r] += (float)iacc[i][0][r] * sf0;                    \
                facc[i][1][r] += (float)iacc[i][1][r] * sf1;                    \
            }                                                                   \
    }

    STAGE(0, 0)
    // stage scales once: coalesced global read; LDS banks (nl+b)%32 -> 2-way = free
    for (int t = tid; t < 4096; t += 256) {
        int nl = t >> 5, b = t & 31;
        Sl[nl * 33 + b] = scales[(size_t)(nBase + nl) * 32 + b];
    }
    __syncthreads();

    const int NIT = KK / BK;  // 32
    for (int it = 0; it < NIT; it += 2) {
        if (it + 1 < NIT) STAGE(1, it + 1)
        COMPUTE(0, it)
        __syncthreads();
        if (it + 2 < NIT) STAGE(0, it + 2)
        COMPUTE(1, it + 1)
        __syncthreads();
    }

    // epilogue: C/D col = lane&15 (n), row = quad*4 + reg (m); fold q[m]
#pragma unroll
    for (int i = 0; i < 4; ++i) {
        floatx4 qv = *(const floatx4*)(qrow + mBase + i * 16 + quad * 4);
#pragma unroll
        for (int r = 0; r < 4; ++r) {
            int mg = mBase + i * 16 + quad * 4 + r;
            float* orow = out + (size_t)mg * NN + nBase + wn + r16;
#pragma unroll
            for (int j = 0; j < 2; ++j) orow[j * 16] = facc[i][j][r] * qv[r];
        }
    }
#undef STAGE
#undef COMPUTE
}

extern "C" void kernel_launch(void* const* d_in, const int* in_sizes, int n_in,
                              void* d_out, int out_size, void* d_ws, size_t ws_size,
                              hipStream_t stream) {
    const float* x      = (const float*)d_in[0];
    const int*   wq     = (const int*)d_in[1];
    const float* scales = (const float*)d_in[2];
    float*       out    = (float*)d_out;

    char*  xq   = (char*)d_ws;                                   // 4 MB
    float* qrow = (float*)((char*)d_ws + (size_t)MM * KK);       // 4 KB
    char*  wb   = (char*)d_ws + (size_t)MM * KK + 4096;          // 16.8 MB

    prep<<<MM + (size_t)NN * KK / 16 / 256, 256, 0, stream>>>(x, wq, xq, qrow, wb);
    q8_gemm<<<(MM / 64) * (NN / 128), 256, 0, stream>>>(xq, wb, qrow, scales, out);
}

// Round 11
// 141.676 us; speedup vs baseline: 1.7235x; 1.3004x over previous
//
#include <hip/hip_runtime.h>
#include <stdint.h>

// Q2Linear int8 path, 2 dispatches — R11 = R7 restored (best verified: 145.8 us).
//   prep: blocks 0..1023    — per-row quantize x fp32 -> i8 (q = rowmax/127)
//         blocks 1024..5119 — pack w int32 {-2..1} -> i8 (exact, coalesced)
//   q8_gemm: i8 MFMA 16x16x64, tile 64m x 128n, BK=128 (= one scale block),
//            512 blocks = 2/CU (LDS 64.9 KB). Both A and B staged via
//            global_load_lds(16B) into XOR-swizzled dbuf LDS (0 conflicts).
//            Scales staged once into padded LDS [n][33] so the K-loop has no
//            global loads besides the DMA (keeps the vmcnt prefetch queue clean).
// Post-mortem ledger: R8 2-bit B (VALU on MFMA waves) -36%; R9 64x64/4-blk
// (VGPR 256 balloon, 3x HBM re-read) -2.7x; R10 direct-A (latency exposed) -2x.
// R7 sits at the 2-barrier K-loop plateau (sum of L2+LDS+MFMA floors, partial
// 2-block overlap); past it requires hand-interleaved vmcnt (not HIP-reachable).

#define MM 1024
#define NN 4096
#define KK 4096
#define BK 128

typedef __attribute__((ext_vector_type(4))) int intx4;
typedef __attribute__((ext_vector_type(4))) float floatx4;

typedef const __attribute__((address_space(1))) void global_cvoid;
typedef __attribute__((address_space(3))) void lds_void;

// ---- prep: quantize x (blocks < MM) OR pack w -> i8 --------------------------
__global__ __launch_bounds__(256) void prep(const float* __restrict__ x,
                                            const int* __restrict__ wq,
                                            char* __restrict__ xq,
                                            float* __restrict__ qrow,
                                            char* __restrict__ wb) {
    const int tid = threadIdx.x;
    if (blockIdx.x < MM) {
        const int m = blockIdx.x;
        const float* xr = x + (size_t)m * KK;
        floatx4 v[4];
        float amax = 0.f;
#pragma unroll
        for (int c = 0; c < 4; ++c) {
            v[c] = *(const floatx4*)(xr + (c * 256 + tid) * 4);
#pragma unroll
            for (int e = 0; e < 4; ++e) amax = fmaxf(amax, fabsf(v[c][e]));
        }
#pragma unroll
        for (int off = 32; off; off >>= 1) amax = fmaxf(amax, __shfl_down(amax, off));
        __shared__ float wmax[4];
        if ((tid & 63) == 0) wmax[tid >> 6] = amax;
        __syncthreads();
        amax = fmaxf(fmaxf(wmax[0], wmax[1]), fmaxf(wmax[2], wmax[3]));
        amax = fmaxf(amax, 1e-20f);
        const float qinv = 127.0f / amax;
        if (tid == 0) qrow[m] = amax / 127.0f;
#pragma unroll
        for (int c = 0; c < 4; ++c) {
            int p = 0;
#pragma unroll
            for (int e = 0; e < 4; ++e) {
                float r = rintf(v[c][e] * qinv);
                r = fminf(fmaxf(r, -127.f), 127.f);
                p |= ((int)r & 255) << (8 * e);
            }
            *(int*)(xq + (size_t)m * KK + (c * 256 + tid) * 4) = p;
        }
    } else {
        // pack w: fully coalesced (lane-consecutive 16B reads / 4B writes)
        const int blk = blockIdx.x - MM;
#pragma unroll
        for (int c = 0; c < 4; ++c) {
            size_t c4 = (size_t)blk * 1024 + c * 256 + tid;  // intx4-chunk id
            intx4 a = ((const intx4*)wq)[c4];
            ((int*)wb)[c4] = (a[0] & 255) | ((a[1] & 255) << 8) |
                             ((a[2] & 255) << 16) | (a[3] << 24);
        }
    }
}

// ---- GEMM: 64x128 tile, 4 waves (each 64m x 32n), double-buffered LDS --------
__global__ __launch_bounds__(256, 2) void q8_gemm(const char* __restrict__ xq,
                                                  const char* __restrict__ wb,
                                                  const float* __restrict__ qrow,
                                                  const float* __restrict__ scales,
                                                  float* __restrict__ out) {
    __shared__ char As[2][64 * BK];    // 8 KB each
    __shared__ char Bs[2][128 * BK];   // 16 KB each
    __shared__ float Sl[128 * 33];     // scales [n_local][block], +1 pad (16.9 KB)
    // total 64.9 KB -> 2 blocks/CU

    const int tid  = threadIdx.x;
    const int lane = tid & 63;
    const int wave = tid >> 6;
    const int r16  = lane & 15;
    const int quad = lane >> 4;
    const int sw   = r16 & 7;
    const int wn   = wave * 32;        // wave's n offset within tile

    // XCD pinning: bid&7 -> XCD; each XCD owns 4 n-tiles (512 cols, 2MB i8 B-strip)
    const int bid = blockIdx.x;
    const int xcd = bid & 7, loc = bid >> 3;   // loc 0..63
    const int nT = xcd * 4 + (loc & 3);        // 0..31
    const int mT = loc >> 2;                   // 0..15
    const int mBase = mT * 64, nBase = nT * 128;

    // staging address permute -> XOR-swizzled LDS tile (verified, 0 conflicts)
    const int rg = lane >> 3;
    const int cs = (lane & 7) ^ rg;
    const char* gA = xq + (size_t)(mBase + wave * 16 + rg) * KK + cs * 16;
    const char* gB = wb + (size_t)(nBase + wave * 32 + rg) * KK + cs * 16;
    const int ldsRowA = wave * 16;
    const int ldsRowB = wave * 32;

    floatx4 facc[4][2];
#pragma unroll
    for (int i = 0; i < 4; ++i)
#pragma unroll
        for (int j = 0; j < 2; ++j) facc[i][j] = (floatx4){0.f, 0.f, 0.f, 0.f};

#define STAGE(BUF, SLAB)                                                        \
    {                                                                           \
        _Pragma("unroll")                                                       \
        for (int t = 0; t < 2; ++t)                                             \
            __builtin_amdgcn_global_load_lds(                                   \
                (global_cvoid*)(gA + (size_t)(t * 8) * KK + (SLAB) * BK),       \
                (lds_void*)&As[BUF][(ldsRowA + t * 8) * BK], 16, 0, 0);         \
        _Pragma("unroll")                                                       \
        for (int t = 0; t < 4; ++t)                                             \
            __builtin_amdgcn_global_load_lds(                                   \
                (global_cvoid*)(gB + (size_t)(t * 8) * KK + (SLAB) * BK),       \
                (lds_void*)&Bs[BUF][(ldsRowB + t * 8) * BK], 16, 0, 0);         \
    }

#define COMPUTE(BUF, SLAB)                                                      \
    {                                                                           \
        float sf0 = Sl[(wn + r16) * 33 + (SLAB)];                               \
        float sf1 = Sl[(wn + 16 + r16) * 33 + (SLAB)];                          \
        intx4 iacc[4][2];                                                       \
        _Pragma("unroll")                                                       \
        for (int kp = 0; kp < 2; ++kp) {                                        \
            intx4 av[4], bv[2];                                                 \
            _Pragma("unroll")                                                   \
            for (int i = 0; i < 4; ++i)                                         \
                av[i] = *(const intx4*)&As[BUF][(i * 16 + r16) * BK +           \
                                               (((kp * 4 + quad) ^ sw) << 4)];  \
            _Pragma("unroll")                                                   \
            for (int j = 0; j < 2; ++j)                                         \
                bv[j] = *(const intx4*)&Bs[BUF][(wn + j * 16 + r16) * BK +      \
                                               (((kp * 4 + quad) ^ sw) << 4)];  \
            _Pragma("unroll")                                                   \
            for (int i = 0; i < 4; ++i)                                         \
                _Pragma("unroll")                                               \
                for (int j = 0; j < 2; ++j)                                     \
                    iacc[i][j] = __builtin_amdgcn_mfma_i32_16x16x64_i8(         \
                        av[i], bv[j], kp ? iacc[i][j] : (intx4){0, 0, 0, 0},    \
                        0, 0, 0);                                               \
        }                                                                       \
        _Pragma("unroll")                                                       \
        for (int i = 0; i < 4; ++i)                                             \
            _Pragma("unroll")                                                   \
            for (int r = 0; r < 4; ++r) {                                       \
                facc[i][0][r] += (float)iacc[i][0][r] * sf0;                    \
                facc[i][1][r] += (float)iacc[i][1][r] * sf1;                    \
            }                                                                   \
    }

    STAGE(0, 0)
    // stage scales once: coalesced global read; LDS banks (nl+b)%32 -> 2-way = free
    for (int t = tid; t < 4096; t += 256) {
        int nl = t >> 5, b = t & 31;
        Sl[nl * 33 + b] = scales[(size_t)(nBase + nl) * 32 + b];
    }
    __syncthreads();

    const int NIT = KK / BK;  // 32
    for (int it = 0; it < NIT; it += 2) {
        if (it + 1 < NIT) STAGE(1, it + 1)
        COMPUTE(0, it)
        __syncthreads();
        if (it + 2 < NIT) STAGE(0, it + 2)
        COMPUTE(1, it + 1)
        __syncthreads();
    }

    // epilogue: C/D col = lane&15 (n), row = quad*4 + reg (m); fold q[m]
#pragma unroll
    for (int i = 0; i < 4; ++i) {
        floatx4 qv = *(const floatx4*)(qrow + mBase + i * 16 + quad * 4);
#pragma unroll
        for (int r = 0; r < 4; ++r) {
            int mg = mBase + i * 16 + quad * 4 + r;
            float* orow = out + (size_t)mg * NN + nBase + wn + r16;
#pragma unroll
            for (int j = 0; j < 2; ++j) orow[j * 16] = facc[i][j][r] * qv[r];
        }
    }
#undef STAGE
#undef COMPUTE
}

extern "C" void kernel_launch(void* const* d_in, const int* in_sizes, int n_in,
                              void* d_out, int out_size, void* d_ws, size_t ws_size,
                              hipStream_t stream) {
    const float* x      = (const float*)d_in[0];
    const int*   wq     = (const int*)d_in[1];
    const float* scales = (const float*)d_in[2];
    float*       out    = (float*)d_out;

    char*  xq   = (char*)d_ws;                                   // 4 MB
    float* qrow = (float*)((char*)d_ws + (size_t)MM * KK);       // 4 KB
    char*  wb   = (char*)d_ws + (size_t)MM * KK + 4096;          // 16.8 MB

    prep<<<MM + (size_t)NN * KK / 16 / 256, 256, 0, stream>>>(x, wq, xq, qrow, wb);
    q8_gemm<<<(MM / 64) * (NN / 128), 256, 0, stream>>>(xq, wb, qrow, scales, out);
}